// Round 1
// 469.663 us; speedup vs baseline: 1.0007x; 1.0007x over previous
//
#include <hip/hip_runtime.h>
#include <math.h>

// GEVCanonicalLoss (xi=0.5): mean over 8192x8192 of l + ent
//   u    = min((1 + 0.5*x)^-2 with base clamp, 13.815511)   [exp/log round-trip elided]
//   gi   = 2*exp(-u)/sqrt(u) - 2*sqrt(pi)*erfc(sqrt(u))
//   l    = gi - t*max(x, -2);  ent = t ? ent1 : ent0  (t in {0,1})
// erfc via Abramowitz-Stegun 7.1.26 (|err| <= 1.5e-7), sharing exp(-u).
//
// R6: block-CONTIGUOUS partitioning (each block owns one sequential 128 KB
// span per stream instead of 4 scattered 32 KB grid-stride chunks) +
// loop-carried pointer bump (px += chunk) so load addresses are cheap adds,
// not per-iter 64-bit mul re-derivation. Also s = u*rsq(u) drops one
// quarter-rate sqrt per element. NT loads + UNROLL=8 kept from R4/R5.
// Measured context: dur_us(470) = ~322 us harness ws-poison fills (2 x 1.07GB,
// visible in rocprof, untouchable) + partial kernel (<159 us) + final (~5 us).
// Kernel floor = 536.9 MB read / 6.3 TB/s ~= 85 us.

static constexpr int BLOCK  = 256;
static constexpr int GRID   = 2048;
static constexpr int UNROLL = 8;

typedef float vfloat4 __attribute__((ext_vector_type(4)));
typedef int   vint4   __attribute__((ext_vector_type(4)));

__device__ __forceinline__ float gev_elem(float x, int t, float ent0, float ent1)
{
    const float SQRTPI = 1.7724538509055160273f;
    const float LOG2E  = 1.4426950408889634f;
    const float UMAX   = 13.815511f;            // -logf(1e-6f)
    const float P  = 0.3275911f;
    const float A1 = 0.254829592f;
    const float A2 = -0.284496736f;
    const float A3 = 1.421413741f;
    const float A4 = -1.453152027f;
    const float A5 = 1.061405429f;

    float base = fmaxf(fmaf(0.5f, x, 1.0f), 1e-6f);
    float rb   = __builtin_amdgcn_rcpf(base);
    float u    = fminf(rb * rb, UMAX);

    float rs = __builtin_amdgcn_rsqf(u);           // 1/sqrt(u)
    float s  = u * rs;                             // sqrt(u) via mul: one fewer trans op
    float e  = __builtin_amdgcn_exp2f(-u * LOG2E); // exp(-u)

    float td = __builtin_amdgcn_rcpf(fmaf(P, s, 1.0f));
    float p  = fmaf(td, A5, A4);
    p = fmaf(td, p, A3);
    p = fmaf(td, p, A2);
    p = fmaf(td, p, A1);
    p = p * td;                                    // erfc(s)*exp(u)

    float inner = fmaf(-SQRTPI, p, rs);
    float gi = (e + e) * inner;                    // gammainc_neg(u)

    return gi + (t ? (ent1 - fmaxf(x, -2.0f)) : ent0);
}

__global__ __launch_bounds__(BLOCK) void gev_partial_kernel(
    const vfloat4* __restrict__ x4,
    const vint4*  __restrict__ t4,
    double*      __restrict__ partial,
    long long n4)
{
    const float SQRTPI = 1.7724538509055160273f;
    const float ent0 = 2.0f * (SQRTPI * erfcf(sqrtf(-logf(1e-6f))));
    const float ent1 = 2.0f * (SQRTPI * erfcf(sqrtf(-logf(1.0f - 1e-6f))) - 1.0f);

    const long long chunk   = (long long)BLOCK * UNROLL;   // vfloat4s per block-iter
    const long long nchunks = n4 / chunk;                  // 8192 at n=2^26
    const long long iters   = nchunks / GRID;              // contiguous chunks per block (4)
    const long long rem     = nchunks - iters * GRID;      // 0 at n=2^26

    double sum = 0.0;

    // Contiguous span for this block: iters consecutive chunks.
    {
        const long long span0 = (long long)blockIdx.x * iters * chunk + threadIdx.x;
        const vfloat4* px = x4 + span0;
        const vint4*   pt = t4 + span0;

        for (long long it = 0; it < iters; ++it) {
            vfloat4 xv[UNROLL];
            vint4   tv[UNROLL];
            // issue all 16 nt loads back-to-back before any use
#pragma unroll
            for (int j = 0; j < UNROLL; ++j) {
                xv[j] = __builtin_nontemporal_load(px + j * BLOCK);
                tv[j] = __builtin_nontemporal_load(pt + j * BLOCK);
            }

            float vsum = 0.0f;
#pragma unroll
            for (int j = 0; j < UNROLL; ++j) {
                vsum += gev_elem(xv[j].x, tv[j].x, ent0, ent1);
                vsum += gev_elem(xv[j].y, tv[j].y, ent0, ent1);
                vsum += gev_elem(xv[j].z, tv[j].z, ent0, ent1);
                vsum += gev_elem(xv[j].w, tv[j].w, ent0, ent1);
            }
            sum += (double)vsum;

            px += chunk;
            pt += chunk;
        }
    }

    // Remainder chunks (nchunks not divisible by GRID): block b < rem takes
    // chunk number GRID*iters + b.
    if (blockIdx.x < rem) {
        const long long cbase = (GRID * iters + (long long)blockIdx.x) * chunk
                              + threadIdx.x;
        vfloat4 xv[UNROLL];
        vint4   tv[UNROLL];
#pragma unroll
        for (int j = 0; j < UNROLL; ++j) {
            xv[j] = __builtin_nontemporal_load(&x4[cbase + (long long)j * BLOCK]);
            tv[j] = __builtin_nontemporal_load(&t4[cbase + (long long)j * BLOCK]);
        }
        float vsum = 0.0f;
#pragma unroll
        for (int j = 0; j < UNROLL; ++j) {
            vsum += gev_elem(xv[j].x, tv[j].x, ent0, ent1);
            vsum += gev_elem(xv[j].y, tv[j].y, ent0, ent1);
            vsum += gev_elem(xv[j].z, tv[j].z, ent0, ent1);
            vsum += gev_elem(xv[j].w, tv[j].w, ent0, ent1);
        }
        sum += (double)vsum;
    }

    // scalar tail (n4 not divisible by chunk): block 0 mops up, strided
    long long done = nchunks * chunk;
    if (blockIdx.x == 0) {
        for (long long i = done + threadIdx.x; i < n4; i += BLOCK) {
            vfloat4 xv = x4[i];
            vint4   tv = t4[i];
            float vsum = gev_elem(xv.x, tv.x, ent0, ent1)
                       + gev_elem(xv.y, tv.y, ent0, ent1)
                       + gev_elem(xv.z, tv.z, ent0, ent1)
                       + gev_elem(xv.w, tv.w, ent0, ent1);
            sum += (double)vsum;
        }
    }

    // wave reduce (64 lanes)
    for (int off = 32; off > 0; off >>= 1)
        sum += __shfl_down(sum, off);

    __shared__ double lds[BLOCK / 64];
    int wave = threadIdx.x >> 6;
    int lane = threadIdx.x & 63;
    if (lane == 0) lds[wave] = sum;
    __syncthreads();
    if (threadIdx.x == 0) {
        double tot = 0.0;
        for (int wv = 0; wv < BLOCK / 64; ++wv) tot += lds[wv];
        partial[blockIdx.x] = tot;
    }
}

__global__ __launch_bounds__(BLOCK) void gev_final_kernel(
    const double* __restrict__ partial,
    float*        __restrict__ out,
    int nblocks,
    double inv_n)
{
    double sum = 0.0;
    for (int i = threadIdx.x; i < nblocks; i += blockDim.x)
        sum += partial[i];

    for (int off = 32; off > 0; off >>= 1)
        sum += __shfl_down(sum, off);

    __shared__ double lds[BLOCK / 64];
    int wave = threadIdx.x >> 6;
    int lane = threadIdx.x & 63;
    if (lane == 0) lds[wave] = sum;
    __syncthreads();
    if (threadIdx.x == 0) {
        double tot = 0.0;
        for (int wv = 0; wv < BLOCK / 64; ++wv) tot += lds[wv];
        out[0] = (float)(tot * inv_n);
    }
}

extern "C" void kernel_launch(void* const* d_in, const int* in_sizes, int n_in,
                              void* d_out, int out_size, void* d_ws, size_t ws_size,
                              hipStream_t stream)
{
    const float* x = (const float*)d_in[0];
    const int*   t = (const int*)d_in[1];
    float* out = (float*)d_out;

    long long n  = (long long)in_sizes[0];   // 8192*8192, divisible by 4
    long long n4 = n >> 2;

    double* partial = (double*)d_ws;

    gev_partial_kernel<<<GRID, BLOCK, 0, stream>>>(
        (const vfloat4*)x, (const vint4*)t, partial, n4);

    gev_final_kernel<<<1, BLOCK, 0, stream>>>(
        partial, out, GRID, 1.0 / (double)n);
}